// Round 4
// baseline (29428.958 us; speedup 1.0000x reference)
//
#include <hip/hip_runtime.h>
#include <cstdint>

#define T_STEPS 8192
#define HDIM    1024

typedef float        f32x4 __attribute__((ext_vector_type(4)));
typedef unsigned int u32x4 __attribute__((ext_vector_type(4)));

__device__ __forceinline__ float dot4(f32x4 a, f32x4 b) {
    return a[0] * b[0] + a[1] * b[1] + a[2] * b[2] + a[3] * b[3];
}
__device__ __forceinline__ float sigmoidf_(float v) { return 1.0f / (1.0f + __expf(-v)); }
__device__ __forceinline__ float tanhf_(float v)    { return 1.0f - 2.0f / (__expf(2.0f * v) + 1.0f); }

// ================= phase 1: gxT[b][t][q*4+r] = x[t]·W_ih[1024q+4b+r] + bias =================
// 64x64 output tile per block, BK=16, 256 threads, 4x4 microtile. f32 VALU GEMM.
__global__ __launch_bounds__(256)
void gemm_gx(const float* __restrict__ x, const float* __restrict__ W_ih,
             const float* __restrict__ b_ih, const float* __restrict__ b_hh,
             float* __restrict__ gxT)
{
    __shared__ float a_s[16][68];
    __shared__ float b_s[16][68];
    const int t  = threadIdx.x;
    const int bm = blockIdx.x >> 6;      // 128 m-tiles (t dimension)
    const int bn = blockIdx.x & 63;      // 64  n-tiles (gate-unit dimension)
    const int m0 = bm << 6, n0 = bn << 6;
    const int tx = t & 15, ty = t >> 4;
    const int lm = t >> 2;               // 0..63
    const int lk = (t & 3) << 2;         // 0,4,8,12

    float acc[4][4] = {};
    for (int k0 = 0; k0 < 1024; k0 += 16) {
        f32x4 av = *(const f32x4*)(x    + (size_t)(m0 + lm) * 1024 + k0 + lk);
        f32x4 bv = *(const f32x4*)(W_ih + (size_t)(n0 + lm) * 1024 + k0 + lk);
        __syncthreads();
#pragma unroll
        for (int j = 0; j < 4; ++j) { a_s[lk + j][lm] = av[j]; b_s[lk + j][lm] = bv[j]; }
        __syncthreads();
#pragma unroll
        for (int k = 0; k < 16; ++k) {
            f32x4 af = *(const f32x4*)&a_s[k][4 * ty];
            f32x4 bf = *(const f32x4*)&b_s[k][4 * tx];
#pragma unroll
            for (int i = 0; i < 4; ++i)
#pragma unroll
                for (int j = 0; j < 4; ++j) acc[i][j] += af[i] * bf[j];
        }
    }
    f32x4 bi = *(const f32x4*)&b_ih[n0 + 4 * tx];
    f32x4 bh = *(const f32x4*)&b_hh[n0 + 4 * tx];
#pragma unroll
    for (int j = 0; j < 4; ++j) {
        const int n = n0 + 4 * tx + j;
        const float bias = bi[j] + bh[j];
        const int q = n >> 10, cidx = n & 1023;
        const int bg = cidx >> 2, r = cidx & 3;
#pragma unroll
        for (int i = 0; i < 4; ++i) {
            const int m = m0 + 4 * ty + i;
            gxT[((size_t)bg * T_STEPS + m) * 16 + q * 4 + r] = acc[i][j] + bias;
        }
    }
}

// ================= phase 2: persistent recurrent loop =================
// 256 blocks x 256 threads. Wave w owns unit u = 4b+w. Only whh (64 VGPR)
// is loop-resident; gx comes from gxT (one 64B line/step, prefetch dist 2).
__global__ __launch_bounds__(256, 1)
void lstm_loop(const float* __restrict__ W_hh,
               const float* __restrict__ h0,
               const float* __restrict__ c0,
               const float* __restrict__ gxT,
               float* __restrict__ out,
               unsigned long long* __restrict__ ring)
{
    __shared__ float h_lds[2][HDIM];

    const int tid = threadIdx.x;
    const int w   = tid >> 6;
    const int l   = tid & 63;
    const int u   = (blockIdx.x << 2) + w;

    f32x4 whh[16];
#pragma unroll
    for (int q = 0; q < 4; ++q) {
        const float* rh = W_hh + (size_t)(q * HDIM + u) * HDIM + 4 * l;
#pragma unroll
        for (int i = 0; i < 4; ++i) whh[q * 4 + i] = *(const f32x4*)(rh + 256 * i);
    }
    asm volatile("" : "+v"(whh[0]), "+v"(whh[1]), "+v"(whh[2]), "+v"(whh[3]),
                      "+v"(whh[4]), "+v"(whh[5]), "+v"(whh[6]), "+v"(whh[7]),
                      "+v"(whh[8]), "+v"(whh[9]), "+v"(whh[10]), "+v"(whh[11]),
                      "+v"(whh[12]), "+v"(whh[13]), "+v"(whh[14]), "+v"(whh[15]));

    float c = c0[u];
    f32x4 hr[4];
#pragma unroll
    for (int i = 0; i < 4; ++i) hr[i] = *(const f32x4*)(h0 + 4 * l + 256 * i);

    const float* gxb = gxT + (size_t)blockIdx.x * T_STEPS * 16;
    const int le = l & 15;
    float gxA = gxb[le];            // step 0
    float gxB = gxb[16 + le];       // step 1
    float gxC = 0.f;

    for (int t = 0; t < T_STEPS; ++t) {
        float acc[4];
#pragma unroll
        for (int q = 0; q < 4; ++q) {
            float a = 0.f;
#pragma unroll
            for (int i = 0; i < 4; ++i) a += dot4(whh[q * 4 + i], hr[i]);
            acc[q] = a;
        }
#pragma unroll
        for (int m = 1; m < 64; m <<= 1) {
#pragma unroll
            for (int q = 0; q < 4; ++q) acc[q] += __shfl_xor(acc[q], m, 64);
        }
        // add gx (contains x·Wih + both biases); element 4q+w rides in lane 4q+w
        const float gi = sigmoidf_(acc[0] + __shfl(gxA, 0 + w, 64));
        const float gf = sigmoidf_(acc[1] + __shfl(gxA, 4 + w, 64));
        const float gg = tanhf_   (acc[2] + __shfl(gxA, 8 + w, 64));
        const float go = sigmoidf_(acc[3] + __shfl(gxA, 12 + w, 64));
        c = gf * c + gi * gg;
        const float hval = go * tanhf_(c);

        if (l == 0) {
            const unsigned long long pk =
                ((unsigned long long)(unsigned)(t + 1) << 32) |
                (unsigned long long)__float_as_uint(hval);
            __hip_atomic_store(&ring[(t & 1) * HDIM + u], pk,
                               __ATOMIC_RELAXED, __HIP_MEMORY_SCOPE_AGENT);
            out[(size_t)t * HDIM + u] = hval;
        }
        if (t == T_STEPS - 1) break;

        // prefetch gx[t+2] (64B line; latency hidden under the poll wait)
        {
            const int tn = (t + 2 < T_STEPS) ? (t + 2) : (T_STEPS - 1);
            gxC = gxb[(size_t)tn * 16 + le];
        }

        // wait for h_t: one 32B coherent read per poll, s_sleep between polls
        {
            const unsigned e = (unsigned)(t + 1);
            const unsigned long long base =
                (unsigned long long)(ring + (t & 1) * HDIM + 4 * tid);
            u32x4 p0, p1;
            for (;;) {
                asm volatile(
                    "global_load_dwordx4 %0, %2, off sc0 sc1\n\t"
                    "global_load_dwordx4 %1, %2, off offset:16 sc0 sc1\n\t"
                    "s_waitcnt vmcnt(0)"
                    : "=&v"(p0), "=&v"(p1)
                    : "v"(base)
                    : "memory");
                if (p0[1] == e && p0[3] == e && p1[1] == e && p1[3] == e) break;
                __builtin_amdgcn_s_sleep(1);
            }
            const int ns = (t + 1) & 1;
            f32x4 hv;
            hv[0] = __uint_as_float(p0[0]);
            hv[1] = __uint_as_float(p0[2]);
            hv[2] = __uint_as_float(p1[0]);
            hv[3] = __uint_as_float(p1[2]);
            *(f32x4*)&h_lds[ns][4 * tid] = hv;
        }
        __syncthreads();
        {
            const int ns = (t + 1) & 1;
#pragma unroll
            for (int i = 0; i < 4; ++i)
                hr[i] = *(const f32x4*)&h_lds[ns][4 * l + 256 * i];
        }
        gxA = gxB; gxB = gxC;
    }
}

// ================= fallback (proven R3 kernel) if ws is too small =================
__global__ __launch_bounds__(256, 1)
void lstm_fb(const float* __restrict__ x, const float* __restrict__ W_ih,
             const float* __restrict__ W_hh, const float* __restrict__ b_ih,
             const float* __restrict__ b_hh, const float* __restrict__ h0,
             const float* __restrict__ c0, float* __restrict__ out,
             unsigned long long* __restrict__ ring)
{
    __shared__ float h_lds[2][HDIM];
    const int tid = threadIdx.x, w = tid >> 6, l = tid & 63;
    const int u = (blockIdx.x << 2) + w;

    f32x4 whh[16], wih[16];
#pragma unroll
    for (int q = 0; q < 4; ++q) {
        const float* rh = W_hh + (size_t)(q * HDIM + u) * HDIM + 4 * l;
        const float* ri = W_ih + (size_t)(q * HDIM + u) * HDIM + 4 * l;
#pragma unroll
        for (int i = 0; i < 4; ++i) {
            whh[q * 4 + i] = *(const f32x4*)(rh + 256 * i);
            wih[q * 4 + i] = *(const f32x4*)(ri + 256 * i);
        }
    }
    float bias[4];
#pragma unroll
    for (int q = 0; q < 4; ++q) bias[q] = b_ih[q * HDIM + u] + b_hh[q * HDIM + u];
    float c = c0[u];
    f32x4 hr[4];
#pragma unroll
    for (int i = 0; i < 4; ++i) hr[i] = *(const f32x4*)(h0 + 4 * l + 256 * i);

    float gxp[4];
    {
        f32x4 x0[4];
#pragma unroll
        for (int i = 0; i < 4; ++i) x0[i] = *(const f32x4*)(x + 4 * l + 256 * i);
#pragma unroll
        for (int q = 0; q < 4; ++q) {
            float a = 0.f;
#pragma unroll
            for (int i = 0; i < 4; ++i) a += dot4(wih[q * 4 + i], x0[i]);
            gxp[q] = a;
        }
    }
    f32x4 xr[4], xn[4];
#pragma unroll
    for (int i = 0; i < 4; ++i) xr[i] = *(const f32x4*)(x + HDIM + 4 * l + 256 * i);

    for (int t = 0; t < T_STEPS; ++t) {
        float acc[4];
#pragma unroll
        for (int q = 0; q < 4; ++q) {
            float a = gxp[q];
#pragma unroll
            for (int i = 0; i < 4; ++i) a += dot4(whh[q * 4 + i], hr[i]);
            acc[q] = a;
        }
#pragma unroll
        for (int m = 1; m < 64; m <<= 1) {
#pragma unroll
            for (int q = 0; q < 4; ++q) acc[q] += __shfl_xor(acc[q], m, 64);
        }
        const float gi = sigmoidf_(acc[0] + bias[0]);
        const float gf = sigmoidf_(acc[1] + bias[1]);
        const float gg = tanhf_   (acc[2] + bias[2]);
        const float go = sigmoidf_(acc[3] + bias[3]);
        c = gf * c + gi * gg;
        const float hval = go * tanhf_(c);
        if (l == 0) {
            const unsigned long long pk =
                ((unsigned long long)(unsigned)(t + 1) << 32) |
                (unsigned long long)__float_as_uint(hval);
            __hip_atomic_store(&ring[(t & 1) * HDIM + u], pk,
                               __ATOMIC_RELAXED, __HIP_MEMORY_SCOPE_AGENT);
            out[(size_t)t * HDIM + u] = hval;
        }
        if (t == T_STEPS - 1) break;
        {
            const int tn = (t + 2 < T_STEPS) ? (t + 2) : (T_STEPS - 1);
            const float* xp = x + (size_t)tn * HDIM;
#pragma unroll
            for (int i = 0; i < 4; ++i) xn[i] = *(const f32x4*)(xp + 4 * l + 256 * i);
        }
#pragma unroll
        for (int q = 0; q < 4; ++q) {
            float a = 0.f;
#pragma unroll
            for (int i = 0; i < 4; ++i) a += dot4(wih[q * 4 + i], xr[i]);
            gxp[q] = a;
        }
        {
            const unsigned e = (unsigned)(t + 1);
            const unsigned long long base =
                (unsigned long long)(ring + (t & 1) * HDIM + 4 * tid);
            u32x4 p0, p1;
            for (;;) {
                asm volatile(
                    "global_load_dwordx4 %0, %2, off sc0 sc1\n\t"
                    "global_load_dwordx4 %1, %2, off offset:16 sc0 sc1\n\t"
                    "s_waitcnt vmcnt(0)"
                    : "=&v"(p0), "=&v"(p1) : "v"(base) : "memory");
                if (p0[1] == e && p0[3] == e && p1[1] == e && p1[3] == e) break;
            }
            const int ns = (t + 1) & 1;
            f32x4 hv;
            hv[0] = __uint_as_float(p0[0]);
            hv[1] = __uint_as_float(p0[2]);
            hv[2] = __uint_as_float(p1[0]);
            hv[3] = __uint_as_float(p1[2]);
            *(f32x4*)&h_lds[ns][4 * tid] = hv;
        }
        __syncthreads();
        {
            const int ns = (t + 1) & 1;
#pragma unroll
            for (int i = 0; i < 4; ++i)
                hr[i] = *(const f32x4*)&h_lds[ns][4 * l + 256 * i];
        }
#pragma unroll
        for (int i = 0; i < 4; ++i) xr[i] = xn[i];
    }
}

extern "C" void kernel_launch(void* const* d_in, const int* in_sizes, int n_in,
                              void* d_out, int out_size, void* d_ws, size_t ws_size,
                              hipStream_t stream)
{
    const float* x    = (const float*)d_in[0];
    const float* W_ih = (const float*)d_in[1];
    const float* W_hh = (const float*)d_in[2];
    const float* b_ih = (const float*)d_in[3];
    const float* b_hh = (const float*)d_in[4];
    const float* h0   = (const float*)d_in[5];
    const float* c0   = (const float*)d_in[6];

    unsigned long long* ring = (unsigned long long*)d_ws;
    hipMemsetAsync(d_ws, 0, 2 * HDIM * sizeof(unsigned long long), stream);

    const size_t need = (size_t)(1u << 20) + (size_t)256 * T_STEPS * 16 * sizeof(float);
    if (ws_size >= need) {
        float* gxT = (float*)((char*)d_ws + (1u << 20));
        gemm_gx<<<8192, 256, 0, stream>>>(x, W_ih, b_ih, b_hh, gxT);
        lstm_loop<<<256, 256, 0, stream>>>(W_hh, h0, c0, gxT, (float*)d_out, ring);
    } else {
        lstm_fb<<<256, 256, 0, stream>>>(x, W_ih, W_hh, b_ih, b_hh, h0, c0,
                                         (float*)d_out, ring);
    }
}

// Round 5
// 24497.781 us; speedup vs baseline: 1.2013x; 1.2013x over previous
//
#include <hip/hip_runtime.h>
#include <cstdint>

#define T_STEPS 8192
#define HDIM    1024
#define NBLK    256
#define NTHR    256

typedef float        f32x4 __attribute__((ext_vector_type(4)));
typedef unsigned int u32x4 __attribute__((ext_vector_type(4)));

__device__ __forceinline__ float dot4(f32x4 a, f32x4 b) {
    return a[0] * b[0] + a[1] * b[1] + a[2] * b[2] + a[3] * b[3];
}
__device__ __forceinline__ float sigmoidf_(float v) { return 1.0f / (1.0f + __expf(-v)); }
__device__ __forceinline__ float tanhf_(float v)    { return 1.0f - 2.0f / (__expf(2.0f * v) + 1.0f); }

// 256 blocks x 256 threads, persistent, 1 wave/SIMD BY CONSTRUCTION.
// amdgpu_waves_per_eu(1,1) raises the compiler's VGPR budget to 512 so the
// 128 weight VGPRs (whh+wih) can actually stay register-resident — R1-R4's
// VGPR_Count of 104/112/104/56 proved the default ~128-reg occupancy target
// was forcing a 16.7MB/step weight re-stream (the real bottleneck).
// Handoff: packed (epoch<<32 | f32) u64 per unit, 2-slot ring in d_ws;
// device-scope (sc1) loads/stores — coherent at the memory-side L3.
__global__ __launch_bounds__(NTHR)
__attribute__((amdgpu_waves_per_eu(1, 1)))
void lstm_persistent(const float* __restrict__ x,
                     const float* __restrict__ W_ih,
                     const float* __restrict__ W_hh,
                     const float* __restrict__ b_ih,
                     const float* __restrict__ b_hh,
                     const float* __restrict__ h0,
                     const float* __restrict__ c0,
                     float* __restrict__ out,
                     unsigned long long* __restrict__ ring)
{
    __shared__ float h_lds[2][HDIM];

    const int tid = threadIdx.x;
    const int w   = tid >> 6;   // wave 0..3
    const int l   = tid & 63;   // lane
    const int u   = (blockIdx.x << 2) + w;

    // ---- load weights once: lane l covers elements 4l + 256i (+j) ----
    f32x4 whh[16], wih[16];
#pragma unroll
    for (int q = 0; q < 4; ++q) {
        const float* rh = W_hh + (size_t)(q * HDIM + u) * HDIM + 4 * l;
        const float* ri = W_ih + (size_t)(q * HDIM + u) * HDIM + 4 * l;
#pragma unroll
        for (int i = 0; i < 4; ++i) {
            whh[q * 4 + i] = *(const f32x4*)(rh + 256 * i);
            wih[q * 4 + i] = *(const f32x4*)(ri + 256 * i);
        }
    }
    // anti-rematerialization pins (one asm each so all 64+64 regs stay live)
    asm volatile("" : "+v"(whh[0]), "+v"(whh[1]), "+v"(whh[2]), "+v"(whh[3]),
                      "+v"(whh[4]), "+v"(whh[5]), "+v"(whh[6]), "+v"(whh[7]),
                      "+v"(whh[8]), "+v"(whh[9]), "+v"(whh[10]), "+v"(whh[11]),
                      "+v"(whh[12]), "+v"(whh[13]), "+v"(whh[14]), "+v"(whh[15]));
    asm volatile("" : "+v"(wih[0]), "+v"(wih[1]), "+v"(wih[2]), "+v"(wih[3]),
                      "+v"(wih[4]), "+v"(wih[5]), "+v"(wih[6]), "+v"(wih[7]),
                      "+v"(wih[8]), "+v"(wih[9]), "+v"(wih[10]), "+v"(wih[11]),
                      "+v"(wih[12]), "+v"(wih[13]), "+v"(wih[14]), "+v"(wih[15]));

    float bias[4];
#pragma unroll
    for (int q = 0; q < 4; ++q) bias[q] = b_ih[q * HDIM + u] + b_hh[q * HDIM + u];
    float c = c0[u];  // replicated across the wave

    f32x4 hr[4];
#pragma unroll
    for (int i = 0; i < 4; ++i) hr[i] = *(const f32x4*)(h0 + 4 * l + 256 * i);

    // x pipeline: gxp = Wih partials for step t; xr = x[t+1]; xn = x[t+2]
    float gxp[4];
    {
        f32x4 x0[4];
#pragma unroll
        for (int i = 0; i < 4; ++i) x0[i] = *(const f32x4*)(x + 4 * l + 256 * i);
#pragma unroll
        for (int q = 0; q < 4; ++q) {
            float a = 0.f;
#pragma unroll
            for (int i = 0; i < 4; ++i) a += dot4(wih[q * 4 + i], x0[i]);
            gxp[q] = a;
        }
    }
    f32x4 xr[4], xn[4];
#pragma unroll
    for (int i = 0; i < 4; ++i) xr[i] = *(const f32x4*)(x + HDIM + 4 * l + 256 * i);

    for (int t = 0; t < T_STEPS; ++t) {
        // gates = gxp + Whh . h_{t-1}
        float acc[4];
#pragma unroll
        for (int q = 0; q < 4; ++q) {
            float a = gxp[q];
#pragma unroll
            for (int i = 0; i < 4; ++i) a += dot4(whh[q * 4 + i], hr[i]);
            acc[q] = a;
        }
#pragma unroll
        for (int m = 1; m < 64; m <<= 1) {
#pragma unroll
            for (int q = 0; q < 4; ++q) acc[q] += __shfl_xor(acc[q], m, 64);
        }
        const float gi = sigmoidf_(acc[0] + bias[0]);
        const float gf = sigmoidf_(acc[1] + bias[1]);
        const float gg = tanhf_   (acc[2] + bias[2]);
        const float go = sigmoidf_(acc[3] + bias[3]);
        c = gf * c + gi * gg;
        const float hval = go * tanhf_(c);

        if (l == 0) {
            const unsigned long long pk =
                ((unsigned long long)(unsigned)(t + 1) << 32) |
                (unsigned long long)__float_as_uint(hval);
            // device-scope store: visible at L3 to all XCDs
            asm volatile("global_store_dwordx2 %0, %1, off sc1"
                         :: "v"((unsigned long long)&ring[(t & 1) * HDIM + u]),
                            "v"(pk) : "memory");
            out[(size_t)t * HDIM + u] = hval;
        }
        if (t == T_STEPS - 1) break;

        // x[t+2] prefetch (latency absorbed by the poll's vmcnt once)
        {
            const int tn = (t + 2 < T_STEPS) ? (t + 2) : (T_STEPS - 1);
            const float* xp = x + (size_t)tn * HDIM;
#pragma unroll
            for (int i = 0; i < 4; ++i) xn[i] = *(const f32x4*)(xp + 4 * l + 256 * i);
        }
        // gx partials for step t+1 (independent of h_t)
#pragma unroll
        for (int q = 0; q < 4; ++q) {
            float a = 0.f;
#pragma unroll
            for (int i = 0; i < 4; ++i) a += dot4(wih[q * 4 + i], xr[i]);
            gxp[q] = a;
        }

        // wait for h_t: one 32B device-scope read per poll, s_sleep backoff
        {
            const unsigned e = (unsigned)(t + 1);
            const unsigned long long base =
                (unsigned long long)(ring + (t & 1) * HDIM + 4 * tid);
            u32x4 p0, p1;
            for (;;) {
                asm volatile(
                    "global_load_dwordx4 %0, %2, off sc1\n\t"
                    "global_load_dwordx4 %1, %2, off offset:16 sc1\n\t"
                    "s_waitcnt vmcnt(0)"
                    : "=&v"(p0), "=&v"(p1)
                    : "v"(base)
                    : "memory");
                if (p0[1] == e && p0[3] == e && p1[1] == e && p1[3] == e) break;
                __builtin_amdgcn_s_sleep(1);
            }
            const int ns = (t + 1) & 1;
            f32x4 hv;
            hv[0] = __uint_as_float(p0[0]);
            hv[1] = __uint_as_float(p0[2]);
            hv[2] = __uint_as_float(p1[0]);
            hv[3] = __uint_as_float(p1[2]);
            *(f32x4*)&h_lds[ns][4 * tid] = hv;
        }
        __syncthreads();
        {
            const int ns = (t + 1) & 1;
#pragma unroll
            for (int i = 0; i < 4; ++i)
                hr[i] = *(const f32x4*)&h_lds[ns][4 * l + 256 * i];
        }
#pragma unroll
        for (int i = 0; i < 4; ++i) xr[i] = xn[i];
    }
}

extern "C" void kernel_launch(void* const* d_in, const int* in_sizes, int n_in,
                              void* d_out, int out_size, void* d_ws, size_t ws_size,
                              hipStream_t stream)
{
    const float* x    = (const float*)d_in[0];
    const float* W_ih = (const float*)d_in[1];
    const float* W_hh = (const float*)d_in[2];
    const float* b_ih = (const float*)d_in[3];
    const float* b_hh = (const float*)d_in[4];
    const float* h0   = (const float*)d_in[5];
    const float* c0   = (const float*)d_in[6];

    unsigned long long* ring = (unsigned long long*)d_ws;
    hipMemsetAsync(d_ws, 0, 2 * HDIM * sizeof(unsigned long long), stream);
    lstm_persistent<<<NBLK, NTHR, 0, stream>>>(x, W_ih, W_hh, b_ih, b_hh, h0, c0,
                                               (float*)d_out, ring);
}